// Round 2
// baseline (128.897 us; speedup 1.0000x reference)
//
#include <hip/hip_runtime.h>
#include <hip/hip_bf16.h>
#include <cstdint>

typedef __attribute__((ext_vector_type(8))) __bf16 bf8;
typedef __attribute__((ext_vector_type(4))) float f32x4;

// order-preserving float<->uint maps (for atomicMin/Max on sim values)
__device__ __forceinline__ unsigned mapf(float x){
  unsigned u = __float_as_uint(x);
  return (u & 0x80000000u) ? ~u : (u | 0x80000000u);
}
__device__ __forceinline__ float unmapf(unsigned u){
  return __uint_as_float((u & 0x80000000u) ? (u & 0x7FFFFFFFu) : ~u);
}

__device__ float digammaf_(float x){
  float r = 0.f;
  while (x < 6.f){ r -= 1.f/x; x += 1.f; }
  float inv = 1.f/x, inv2 = inv*inv;
  r += logf(x) - 0.5f*inv
     - inv2*(0.08333333333f - inv2*(0.008333333333f - inv2*0.003968253968f));
  return r;
}

// ============ k_prep: normalize -> fragment-ordered bf16 (fb2) + losses =====
// fb2 layout (MFMA-fragment, LANE order): panel p=row/64 (NCH chunks), chunk
// cc=k/32, sub-block mi=(row%64)/16; within a 512-elem block, element
// (r16=row%16, q=(k%32)/8, j=k%8) lives at (q*16 + r16)*8 + j.
// => k_pairs lane L (quad=L/16,l16=L%16) reads bytes [L*16, L*16+16) of the
// block: quarter-wave = 4 contiguous 64B lines (ideal VMEM coalescing).
__global__ __launch_bounds__(256) void k_prep(const float* __restrict__ feat,
    __bf16* __restrict__ fb2,
    const float* __restrict__ logits, const int* __restrict__ targets,
    const float* __restrict__ alpha,  const float* __restrict__ fa,
    const float* __restrict__ cw, int B, int D,
    float* __restrict__ psum, unsigned* rowMinU, unsigned* rowMaxU){
  int bid = blockIdx.x, tid = threadIdx.x;
  int wave = tid >> 6, lane = tid & 63;

  int row = bid*4 + wave;                       // grid = B/4, always < B
  // ---- normalize one row per wave ----
  const float* src = feat + (size_t)row*D;
  float ss = 0.f;
  for (int c = lane*4; c < D; c += 64*4){
    float4 v = *(const float4*)(src + c);
    ss += v.x*v.x + v.y*v.y + v.z*v.z + v.w*v.w;
  }
  #pragma unroll
  for (int off=32; off; off>>=1) ss += __shfl_xor(ss, off);
  float inv = 1.f / fmaxf(sqrtf(ss), 1e-12f);

  int p = row >> 6, r = row & 63;
  int mi = r >> 4, l16r = r & 15;
  int NCH = D >> 5;
  for (int c = lane*8; c < D; c += 64*8){
    float4 v0 = *(const float4*)(src + c);
    float4 v1 = *(const float4*)(src + c + 4);
    bf8 o;
    o[0]=(__bf16)(v0.x*inv); o[1]=(__bf16)(v0.y*inv);
    o[2]=(__bf16)(v0.z*inv); o[3]=(__bf16)(v0.w*inv);
    o[4]=(__bf16)(v1.x*inv); o[5]=(__bf16)(v1.y*inv);
    o[6]=(__bf16)(v1.z*inv); o[7]=(__bf16)(v1.w*inv);
    int cc = c >> 5;                  // chunk
    int q  = (c >> 3) & 3;            // 8-elem kgroup within chunk
    size_t off = ((size_t)(p*NCH + cc)*4 + mi)*512 + (q*16 + l16r)*8;
    *(bf8*)(fb2 + off) = o;
  }

  // ---- init row min/max (4 rows per block) ----
  if (tid < 4){ rowMinU[bid*4+tid] = 0xFFFFFFFFu; rowMaxU[bid*4+tid] = 0u; }

  // ---- per-sample losses: wave 0 only, lanes 0..3 take the 4 samples ----
  if (wave == 0){
    float r0=0.f,r1=0.f,r2=0.f,r3=0.f,r4=0.f,r5=0.f;
    if (lane < 4){
      int i = bid*4 + lane;
      float l0=logits[3*i], l1=logits[3*i+1], l2=logits[3*i+2];
      int t = targets[i];
      float m = fmaxf(l0, fmaxf(l1,l2));
      float e0=expf(l0-m), e1=expf(l1-m), e2=expf(l2-m);
      float se = e0+e1+e2;
      float lse = m + logf(se);
      float lp0=l0-lse, lp1=l1-lse, lp2=l2-lse;
      float lpt = (t==0)?lp0:((t==1)?lp1:lp2);
      float nll = -lpt;
      float ce_ls = 0.9f*nll + 0.1f*(-(lp0+lp1+lp2)*(1.f/3.f));
      float pt = expf(-ce_ls);
      float om = 1.f - pt;
      float focal_i = fa[t]*om*om*ce_ls;
      float w = cw[t];
      float ce_n = w*nll, ce_d = w;
      float p0=e0/se, p1=e1/se, p2=e2/se;
      float bnd;
      if (t==0)      bnd = p1 + 0.6f*p2;
      else if (t==2) bnd = p1 + 0.4f*p0;
      else           bnd = 4.5f*(1.f - p1 + 0.3f*(p0+p2));
      float a0=alpha[3*i], a1=alpha[3*i+1], a2=alpha[3*i+2];
      float S = a0+a1+a2 + 1e-8f;
      float at_ = (t==0)?a0:((t==1)?a1:a2);
      float lik = digammaf_(S) - digammaf_(at_ + 1e-8f);
      float b0 = (t==0)?1.f:a0, b1 = (t==1)?1.f:a1, b2 = (t==2)?1.f:a2;
      float ats = b0+b1+b2 + 1e-8f;
      float psa = digammaf_(ats + 1e-8f);
      float kl = lgammaf(ats)
         - (lgammaf(b0+1e-8f)+lgammaf(b1+1e-8f)+lgammaf(b2+1e-8f))
         + (b0-1.f)*(digammaf_(b0+1e-8f)-psa)
         + (b1-1.f)*(digammaf_(b1+1e-8f)-psa)
         + (b2-1.f)*(digammaf_(b2+1e-8f)-psa);
      r0=focal_i; r1=ce_n; r2=ce_d; r3=bnd; r4=lik; r5=kl;
    }
    float s0 = ((__shfl(r0,0)+__shfl(r0,1))+__shfl(r0,2))+__shfl(r0,3);
    float s1 = ((__shfl(r1,0)+__shfl(r1,1))+__shfl(r1,2))+__shfl(r1,3);
    float s2 = ((__shfl(r2,0)+__shfl(r2,1))+__shfl(r2,2))+__shfl(r2,3);
    float s3 = ((__shfl(r3,0)+__shfl(r3,1))+__shfl(r3,2))+__shfl(r3,3);
    float s4 = ((__shfl(r4,0)+__shfl(r4,1))+__shfl(r4,2))+__shfl(r4,3);
    float s5 = ((__shfl(r5,0)+__shfl(r5,1))+__shfl(r5,2))+__shfl(r5,3);
    if (lane == 0){
      psum[bid*8+0]=s0; psum[bid*8+1]=s1; psum[bid*8+2]=s2;
      psum[bid*8+3]=s3; psum[bid*8+4]=s4; psum[bid*8+5]=s5;
    }
  }
}

// ============ k_pairs: single-wave 32x32 tiles, LDS-free, high-TLP =========
// Round-1 post-mortem: 64x64 single-wave = 2080 waves = 2/SIMD -> pure
// latency bound (MfmaUtil 5.8%, eff. load BW 5 TB/s << 34.5 L2 ceiling).
// Fix: 32x32 tiles -> 8256 waves (~6/SIMD resident); lane-order fragments
// (each lane reads base+lane*16B: quarter-wave = 4 contiguous lines).
// Same per-element MFMA accumulation order => sim values bit-identical.
__global__ __launch_bounds__(64) void k_pairs(const __bf16* __restrict__ fb2,
    const int* __restrict__ targets, int B, int D,
    float* __restrict__ pairPart, unsigned* rowMinU, unsigned* rowMaxU){
  // decode triangular tile index -> (by, bx), by <= bx
  int t = blockIdx.x;
  int bx = (int)((sqrtf(8.f*(float)t + 1.f) - 1.f)*0.5f);
  while ((bx+1)*(bx+2)/2 <= t) bx++;
  while (bx*(bx+1)/2 > t) bx--;
  int by = t - bx*(bx+1)/2;
  bool isDiag = (by == bx);
  int rowBase = by*32, colBase = bx*32;

  int lane = threadIdx.x;
  int quad = lane >> 4, l16 = lane & 15;
  int NCH = D >> 5;                                 // 16 chunks

  // panel = 64 rows; a 32-tile is half a panel (2 of 4 sub-blocks)
  const __bf16* pA = fb2 + ((size_t)(by>>1)*NCH*4 + (by&1)*2)*512 + lane*8;
  const __bf16* pB = fb2 + ((size_t)(bx>>1)*NCH*4 + (bx&1)*2)*512 + lane*8;

  f32x4 C[2][2] = {};
  bf8 A0[2], B0[2], A1[2], B1[2];

  #define LOADF(AD, BD, it) do{ \
    AD[0] = *(const bf8*)(pA + (size_t)(it)*2048);        \
    AD[1] = *(const bf8*)(pA + (size_t)(it)*2048 + 512);  \
    BD[0] = *(const bf8*)(pB + (size_t)(it)*2048);        \
    BD[1] = *(const bf8*)(pB + (size_t)(it)*2048 + 512);  \
  }while(0)

  #define COMPUTE(AF, BF) do{ \
    _Pragma("unroll") \
    for (int mi=0; mi<2; mi++) \
      _Pragma("unroll") \
      for (int ni=0; ni<2; ni++) \
        C[mi][ni] = __builtin_amdgcn_mfma_f32_16x16x32_bf16(AF[mi], BF[ni], C[mi][ni], 0,0,0); \
  }while(0)

  LOADF(A0, B0, 0);
  for (int it=0; it<NCH; it+=2){
    LOADF(A1, B1, it+1);
    COMPUTE(A0, B0);
    if (it+2 < NCH) LOADF(A0, B0, it+2);
    COMPUTE(A1, B1);
  }
  #undef LOADF
  #undef COMPUTE

  // ---- fused epilogue (same math as validated 64-tile version) ----
  int tcol[2];
  #pragma unroll
  for (int ni=0; ni<2; ni++) tcol[ni] = targets[colBase + ni*16 + l16];

  float pos=0.f, neg=0.f, semi=0.f, diag=0.f;
  float cmin[2], cmax[2];
  #pragma unroll
  for (int ni=0; ni<2; ni++){ cmin[ni]=2.f; cmax[ni]=-2.f; }

  #pragma unroll
  for (int mi=0; mi<2; mi++){
    #pragma unroll
    for (int r=0; r<4; r++){
      int rl = mi*16 + quad*4 + r;
      int row = rowBase + rl;
      int tr = targets[row];
      float vmin = 2.f, vmax = -2.f;
      #pragma unroll
      for (int ni=0; ni<2; ni++){
        int col = colBase + ni*16 + l16;
        float s = C[mi][ni][r];
        if (tr == tcol[ni]){
          float omv = 1.f - s;
          float q = omv*omv;
          pos += q;
          if (tr == 1) semi += q;
          if (row == col) diag += q;     // only possible on diagonal tiles
          else {
            vmin = fminf(vmin, s);
            cmin[ni] = fminf(cmin[ni], s);
          }
        } else {
          float c0 = fmaxf(s - 0.2f, 0.f);
          neg += c0*c0;
          vmax = fmaxf(vmax, s);
          cmax[ni] = fmaxf(cmax[ni], s);
        }
      }
      #pragma unroll
      for (int off=1; off<16; off<<=1){
        vmin = fminf(vmin, __shfl_xor(vmin, off));
        vmax = fmaxf(vmax, __shfl_xor(vmax, off));
      }
      if (l16 == 0){
        atomicMin(&rowMinU[row], mapf(vmin));
        atomicMax(&rowMaxU[row], mapf(vmax));
      }
    }
  }

  if (!isDiag){
    #pragma unroll
    for (int ni=0; ni<2; ni++){
      float cn = cmin[ni], cx = cmax[ni];
      cn = fminf(cn, __shfl_xor(cn, 16)); cn = fminf(cn, __shfl_xor(cn, 32));
      cx = fmaxf(cx, __shfl_xor(cx, 16)); cx = fmaxf(cx, __shfl_xor(cx, 32));
      if (quad == 0){
        int col = colBase + ni*16 + l16;
        atomicMin(&rowMinU[col], mapf(cn));
        atomicMax(&rowMaxU[col], mapf(cx));
      }
    }
  }

  #pragma unroll
  for (int off=32; off; off>>=1){
    pos  += __shfl_xor(pos, off);
    neg  += __shfl_xor(neg, off);
    semi += __shfl_xor(semi, off);
    diag += __shfl_xor(diag, off);
  }
  if (lane == 0){
    float fac = isDiag ? 1.f : 2.f;
    pairPart[blockIdx.x*4+0] = pos*fac;
    pairPart[blockIdx.x*4+1] = neg*fac;
    pairPart[blockIdx.x*4+2] = semi*fac;
    pairPart[blockIdx.x*4+3] = diag;
  }
}

// ============ k_final: 1024 threads; histogram + reductions + combine ======
__global__ __launch_bounds__(1024) void k_final(const int* __restrict__ targets,
    const int* __restrict__ epoch_p, int B, int nprep, int nblk,
    const float* __restrict__ pairPart, const float* __restrict__ psum,
    const unsigned* rowMinU, const unsigned* rowMaxU, float* out){
  int tid = threadIdx.x, wave = tid>>6, lane = tid&63;
  __shared__ float redf[16][8];
  __shared__ int   redi[16][4];
  __shared__ float tot6[6];
  __shared__ int   cns[3];
  __shared__ float ptot[4];

  // ---- 1) histogram targets (int4 loads) ----
  {
    int c0=0,c1=0,c2=0;
    for (int i4 = tid; i4 < B/4; i4 += 1024){
      int4 tv = ((const int4*)targets)[i4];
      c0 += (tv.x==0)+(tv.y==0)+(tv.z==0)+(tv.w==0);
      c1 += (tv.x==1)+(tv.y==1)+(tv.z==1)+(tv.w==1);
      c2 += (tv.x==2)+(tv.y==2)+(tv.z==2)+(tv.w==2);
    }
    #pragma unroll
    for (int off=32; off; off>>=1){
      c0+=__shfl_xor(c0,off); c1+=__shfl_xor(c1,off); c2+=__shfl_xor(c2,off);
    }
    if (lane==0){ redi[wave][0]=c0; redi[wave][1]=c1; redi[wave][2]=c2; }
  }
  // ---- 2) per-sample partials ----
  {
    float v0=0,v1=0,v2=0,v3=0,v4=0,v5=0;
    for (int s = tid; s < nprep; s += 1024){
      float4 a = *(const float4*)(psum + s*8);
      float4 b = *(const float4*)(psum + s*8 + 4);
      v0+=a.x; v1+=a.y; v2+=a.z; v3+=a.w; v4+=b.x; v5+=b.y;
    }
    #pragma unroll
    for (int off=32; off; off>>=1){
      v0+=__shfl_xor(v0,off); v1+=__shfl_xor(v1,off); v2+=__shfl_xor(v2,off);
      v3+=__shfl_xor(v3,off); v4+=__shfl_xor(v4,off); v5+=__shfl_xor(v5,off);
    }
    if (lane==0){
      redf[wave][0]=v0; redf[wave][1]=v1; redf[wave][2]=v2;
      redf[wave][3]=v3; redf[wave][4]=v4; redf[wave][5]=v5;
    }
  }
  __syncthreads();
  if (tid == 0){
    int c0=0,c1=0,c2=0;
    float v[6]={0,0,0,0,0,0};
    for (int w2=0; w2<16; w2++){
      c0+=redi[w2][0]; c1+=redi[w2][1]; c2+=redi[w2][2];
      for (int j=0;j<6;j++) v[j]+=redf[w2][j];
    }
    cns[0]=c0; cns[1]=c1; cns[2]=c2;
    for (int j=0;j<6;j++) tot6[j]=v[j];
  }
  __syncthreads();

  // ---- 3) pair partials ----
  {
    float p=0,n=0,s2=0,d=0;
    for (int s = tid; s < nblk; s += 1024){
      float4 a = *(const float4*)(pairPart + s*4);
      p+=a.x; n+=a.y; s2+=a.z; d+=a.w;
    }
    #pragma unroll
    for (int off=32; off; off>>=1){
      p+=__shfl_xor(p,off); n+=__shfl_xor(n,off);
      s2+=__shfl_xor(s2,off); d+=__shfl_xor(d,off);
    }
    if (lane==0){ redf[wave][0]=p; redf[wave][1]=n; redf[wave][2]=s2; redf[wave][3]=d; }
  }
  __syncthreads();
  if (tid == 0){
    float a=0,b=0,c=0,e=0;
    for (int w2=0; w2<16; w2++){ a+=redf[w2][0]; b+=redf[w2][1]; c+=redf[w2][2]; e+=redf[w2][3]; }
    ptot[0]=a; ptot[1]=b; ptot[2]=c; ptot[3]=e;
  }
  __syncthreads();

  int n0=cns[0], n1=cns[1], n2=cns[2];

  // ---- 4) triplet ----
  float tsum = 0.f, tcnt = 0.f;
  for (int i = tid; i < B; i += 1024){
    int t = targets[i];
    int nt = (t==0)?n0:((t==1)?n1:n2);
    if (nt - 1 > 0 && B - nt > 0){
      float mn = unmapf(rowMinU[i]);
      float mx = unmapf(rowMaxU[i]);
      float hp = sqrtf(fmaxf(2.f - 2.f*mn, 0.f));
      float hn = sqrtf(fmaxf(2.f - 2.f*mx, 0.f));
      float margin = 1.5f * ((t==1) ? 2.5f : 1.f);
      float tl = fmaxf(hp - hn + margin, 0.f);
      tsum += tl; tcnt += 1.f;
    }
  }
  #pragma unroll
  for (int off=32; off; off>>=1){ tsum += __shfl_xor(tsum, off); tcnt += __shfl_xor(tcnt, off); }
  if (lane==0){ redf[wave][6]=tsum; redf[wave][7]=tcnt; }
  __syncthreads();

  if (tid==0){
    float ts=0, tn=0;
    for (int w2=0; w2<16; w2++){ ts+=redf[w2][6]; tn+=redf[w2][7]; }
    float triplet = (tn > 0.f) ? ts / fmaxf(tn, 1.f) : 0.f;
    float pos=ptot[0], neg=ptot[1], semi=ptot[2], diag=ptot[3];
    float Bf = (float)B;
    float focal = tot6[0] / Bf;
    float ce = tot6[1] / tot6[2];
    float boundary = tot6[3] / (Bf + 1e-8f);
    float contrastive = (pos + neg + 4.f*semi) / (Bf*Bf + 1e-8f);
    long long npl = ((long long)n0*(n0-1) + (long long)n1*(n1-1) + (long long)n2*(n2-1))/2;
    float qsum = (pos - diag) * 0.5f;
    float q = qsum / (float)(npl > 0 ? npl : 1);
    if (n2 > 0) q *= (1.f + 2.5f * ((float)n2 / Bf));
    float quality = (npl > 0) ? q : 0.f;
    int ep = epoch_p[0];
    float er = (float)ep / 25.f;
    float ann = fminf(1.f, er*er);
    float evidential = tot6[4]/Bf + ann*0.2f*tot6[5]/Bf;
    float total = 0.4f*focal + 0.3f*ce + 0.15f*boundary
                + 0.1f*contrastive + 0.1f*triplet + 0.1f*quality + 0.1f*evidential;
    out[0] = total;
  }
}

extern "C" void kernel_launch(void* const* d_in, const int* in_sizes, int n_in,
                              void* d_out, int out_size, void* d_ws, size_t ws_size,
                              hipStream_t stream){
  const float* logits   = (const float*)d_in[0];
  const int*   targets  = (const int*)d_in[1];
  const float* features = (const float*)d_in[2];
  const float* alpha    = (const float*)d_in[3];
  const int*   epoch    = (const int*)d_in[4];
  const float* fa       = (const float*)d_in[5];
  const float* cw       = (const float*)d_in[6];
  int B = in_sizes[1];
  int D = in_sizes[2] / B;
  int nprep = B/4;                 // k_prep blocks == psum slots
  int T  = B / 32;                 // 32-row tiles now
  int nblk = T*(T+1)/2;            // triangular: by <= bx  (8256 @ B=4096)

  char* ws = (char*)d_ws;
  float*    psum     = (float*)(ws);                          // nprep*8 f32 (32KB)
  float*    pairPart = (float*)(ws + 65536);                  // nblk*4 f32 (~132KB)
  unsigned* rowMinU  = (unsigned*)(ws + 65536 + 196608);      // B u32
  unsigned* rowMaxU  = (unsigned*)(ws + 65536 + 196608 + (size_t)B*4);
  __bf16*   fb2      = (__bf16*)(ws + 65536 + 196608 + (size_t)B*8);  // B*D bf16

  k_prep <<<nprep, 256, 0, stream>>>(features, fb2, logits, targets, alpha, fa, cw,
                                     B, D, psum, rowMinU, rowMaxU);
  k_pairs<<<nblk, 64, 0, stream>>>(fb2, targets, B, D, pairPart, rowMinU, rowMaxU);
  k_final<<<1, 1024, 0, stream>>>(targets, epoch, B, nprep, nblk, pairPart, psum,
                                  rowMinU, rowMaxU, (float*)d_out);
}

// Round 3
// 122.676 us; speedup vs baseline: 1.0507x; 1.0507x over previous
//
#include <hip/hip_runtime.h>
#include <hip/hip_bf16.h>
#include <cstdint>

typedef __attribute__((ext_vector_type(8))) __bf16 bf8;
typedef __attribute__((ext_vector_type(4))) float f32x4;

// order-preserving float<->uint maps (for atomicMin/Max on sim values)
__device__ __forceinline__ unsigned mapf(float x){
  unsigned u = __float_as_uint(x);
  return (u & 0x80000000u) ? ~u : (u | 0x80000000u);
}
__device__ __forceinline__ float unmapf(unsigned u){
  return __uint_as_float((u & 0x80000000u) ? (u & 0x7FFFFFFFu) : ~u);
}

__device__ float digammaf_(float x){
  float r = 0.f;
  while (x < 6.f){ r -= 1.f/x; x += 1.f; }
  float inv = 1.f/x, inv2 = inv*inv;
  r += logf(x) - 0.5f*inv
     - inv2*(0.08333333333f - inv2*(0.008333333333f - inv2*0.003968253968f));
  return r;
}

// ============ k_prep: normalize -> fragment-ordered bf16 (fb2) + losses =====
// fb2 layout (MFMA-fragment, LANE order): panel p=row/64 (NCH chunks), chunk
// cc=k/32, sub-block mi=(row%64)/16; within a 512-elem block, element
// (r16=row%16, q=(k%32)/8, j=k%8) lives at (q*16 + r16)*8 + j.
// => k_pairs lane L reads bytes [L*16, L*16+16) of the block: quarter-wave =
// 4 contiguous 64B lines (ideal VMEM coalescing).
__global__ __launch_bounds__(256) void k_prep(const float* __restrict__ feat,
    __bf16* __restrict__ fb2,
    const float* __restrict__ logits, const int* __restrict__ targets,
    const float* __restrict__ alpha,  const float* __restrict__ fa,
    const float* __restrict__ cw, int B, int D,
    float* __restrict__ psum, unsigned* rowMinU, unsigned* rowMaxU){
  int bid = blockIdx.x, tid = threadIdx.x;
  int wave = tid >> 6, lane = tid & 63;

  int row = bid*4 + wave;                       // grid = B/4, always < B
  // ---- normalize one row per wave ----
  const float* src = feat + (size_t)row*D;
  float ss = 0.f;
  for (int c = lane*4; c < D; c += 64*4){
    float4 v = *(const float4*)(src + c);
    ss += v.x*v.x + v.y*v.y + v.z*v.z + v.w*v.w;
  }
  #pragma unroll
  for (int off=32; off; off>>=1) ss += __shfl_xor(ss, off);
  float inv = 1.f / fmaxf(sqrtf(ss), 1e-12f);

  int p = row >> 6, r = row & 63;
  int mi = r >> 4, l16r = r & 15;
  int NCH = D >> 5;
  for (int c = lane*8; c < D; c += 64*8){
    float4 v0 = *(const float4*)(src + c);
    float4 v1 = *(const float4*)(src + c + 4);
    bf8 o;
    o[0]=(__bf16)(v0.x*inv); o[1]=(__bf16)(v0.y*inv);
    o[2]=(__bf16)(v0.z*inv); o[3]=(__bf16)(v0.w*inv);
    o[4]=(__bf16)(v1.x*inv); o[5]=(__bf16)(v1.y*inv);
    o[6]=(__bf16)(v1.z*inv); o[7]=(__bf16)(v1.w*inv);
    int cc = c >> 5;                  // chunk
    int q  = (c >> 3) & 3;            // 8-elem kgroup within chunk
    size_t off = ((size_t)(p*NCH + cc)*4 + mi)*512 + (q*16 + l16r)*8;
    *(bf8*)(fb2 + off) = o;
  }

  // ---- init row min/max (4 rows per block) ----
  if (tid < 4){ rowMinU[bid*4+tid] = 0xFFFFFFFFu; rowMaxU[bid*4+tid] = 0u; }

  // ---- per-sample losses: wave 0 only, lanes 0..3 take the 4 samples ----
  if (wave == 0){
    float r0=0.f,r1=0.f,r2=0.f,r3=0.f,r4=0.f,r5=0.f;
    if (lane < 4){
      int i = bid*4 + lane;
      float l0=logits[3*i], l1=logits[3*i+1], l2=logits[3*i+2];
      int t = targets[i];
      float m = fmaxf(l0, fmaxf(l1,l2));
      float e0=expf(l0-m), e1=expf(l1-m), e2=expf(l2-m);
      float se = e0+e1+e2;
      float lse = m + logf(se);
      float lp0=l0-lse, lp1=l1-lse, lp2=l2-lse;
      float lpt = (t==0)?lp0:((t==1)?lp1:lp2);
      float nll = -lpt;
      float ce_ls = 0.9f*nll + 0.1f*(-(lp0+lp1+lp2)*(1.f/3.f));
      float pt = expf(-ce_ls);
      float om = 1.f - pt;
      float focal_i = fa[t]*om*om*ce_ls;
      float w = cw[t];
      float ce_n = w*nll, ce_d = w;
      float p0=e0/se, p1=e1/se, p2=e2/se;
      float bnd;
      if (t==0)      bnd = p1 + 0.6f*p2;
      else if (t==2) bnd = p1 + 0.4f*p0;
      else           bnd = 4.5f*(1.f - p1 + 0.3f*(p0+p2));
      float a0=alpha[3*i], a1=alpha[3*i+1], a2=alpha[3*i+2];
      float S = a0+a1+a2 + 1e-8f;
      float at_ = (t==0)?a0:((t==1)?a1:a2);
      float lik = digammaf_(S) - digammaf_(at_ + 1e-8f);
      float b0 = (t==0)?1.f:a0, b1 = (t==1)?1.f:a1, b2 = (t==2)?1.f:a2;
      float ats = b0+b1+b2 + 1e-8f;
      float psa = digammaf_(ats + 1e-8f);
      float kl = lgammaf(ats)
         - (lgammaf(b0+1e-8f)+lgammaf(b1+1e-8f)+lgammaf(b2+1e-8f))
         + (b0-1.f)*(digammaf_(b0+1e-8f)-psa)
         + (b1-1.f)*(digammaf_(b1+1e-8f)-psa)
         + (b2-1.f)*(digammaf_(b2+1e-8f)-psa);
      r0=focal_i; r1=ce_n; r2=ce_d; r3=bnd; r4=lik; r5=kl;
    }
    float s0 = ((__shfl(r0,0)+__shfl(r0,1))+__shfl(r0,2))+__shfl(r0,3);
    float s1 = ((__shfl(r1,0)+__shfl(r1,1))+__shfl(r1,2))+__shfl(r1,3);
    float s2 = ((__shfl(r2,0)+__shfl(r2,1))+__shfl(r2,2))+__shfl(r2,3);
    float s3 = ((__shfl(r3,0)+__shfl(r3,1))+__shfl(r3,2))+__shfl(r3,3);
    float s4 = ((__shfl(r4,0)+__shfl(r4,1))+__shfl(r4,2))+__shfl(r4,3);
    float s5 = ((__shfl(r5,0)+__shfl(r5,1))+__shfl(r5,2))+__shfl(r5,3);
    if (lane == 0){
      psum[bid*8+0]=s0; psum[bid*8+1]=s1; psum[bid*8+2]=s2;
      psum[bid*8+3]=s3; psum[bid*8+4]=s4; psum[bid*8+5]=s5;
    }
  }
}

// ============ k_pairs: 1 wave computes TWO 32x32 tiles sharing the A panel ==
// Grid: NBY x PMAX rectangular; block (by, p) covers tiles (by, by+2p) and
// (by, by+2p+1). A panel loaded once per pair: traffic 528->400 MB.
// Epilogue: row min/max batched to ONE atomic instr pair per wave (32 lanes),
// col atomics 2 instr/tile (32 lanes), targets[row] via one load + shuffles.
__global__ __launch_bounds__(64, 4) void k_pairs(const __bf16* __restrict__ fb2,
    const int* __restrict__ targets, int B, int D,
    float* __restrict__ pairPart, unsigned* rowMinU, unsigned* rowMaxU){
  int NBY = B >> 5;                 // number of 32-row groups
  int bid = blockIdx.x;
  int by  = bid % NBY;
  int p   = bid / NBY;
  int bx0 = by + 2*p;
  int lane = threadIdx.x;
  if (bx0 >= NBY){                  // inactive pair slot: zero its partials
    if (lane == 0) *(float4*)(pairPart + bid*4) = make_float4(0.f,0.f,0.f,0.f);
    return;
  }
  int bx1 = bx0 + 1;
  bool hasT1 = (bx1 < NBY);
  bool isDiag0 = (bx0 == by);
  int rowBase = by*32, colBase0 = bx0*32, colBase1 = bx1*32;

  int quad = lane >> 4, l16 = lane & 15;
  int NCH = D >> 5;

  const __bf16* pA  = fb2 + ((size_t)(by >>1)*NCH*4 + (by &1)*2)*512 + lane*8;
  const __bf16* pB0 = fb2 + ((size_t)(bx0>>1)*NCH*4 + (bx0&1)*2)*512 + lane*8;
  const __bf16* pB1 = hasT1
      ? fb2 + ((size_t)(bx1>>1)*NCH*4 + (bx1&1)*2)*512 + lane*8
      : pB0;                        // harmless duplicate loads; epi skipped

  f32x4 C0[2][2] = {};
  f32x4 C1[2][2] = {};
  bf8 As0[2], Bs00[2], Bs10[2];
  bf8 As1[2], Bs01[2], Bs11[2];

  #define LOADS(As, B0s, B1s, it) do{ \
    As[0]  = *(const bf8*)(pA  + (size_t)(it)*2048); \
    As[1]  = *(const bf8*)(pA  + (size_t)(it)*2048 + 512); \
    B0s[0] = *(const bf8*)(pB0 + (size_t)(it)*2048); \
    B0s[1] = *(const bf8*)(pB0 + (size_t)(it)*2048 + 512); \
    B1s[0] = *(const bf8*)(pB1 + (size_t)(it)*2048); \
    B1s[1] = *(const bf8*)(pB1 + (size_t)(it)*2048 + 512); \
  }while(0)

  #define COMP(As, B0s, B1s) do{ \
    _Pragma("unroll") \
    for (int mi=0; mi<2; mi++) \
      _Pragma("unroll") \
      for (int ni=0; ni<2; ni++) \
        C0[mi][ni] = __builtin_amdgcn_mfma_f32_16x16x32_bf16(As[mi], B0s[ni], C0[mi][ni], 0,0,0); \
    _Pragma("unroll") \
    for (int mi=0; mi<2; mi++) \
      _Pragma("unroll") \
      for (int ni=0; ni<2; ni++) \
        C1[mi][ni] = __builtin_amdgcn_mfma_f32_16x16x32_bf16(As[mi], B1s[ni], C1[mi][ni], 0,0,0); \
  }while(0)

  LOADS(As0, Bs00, Bs10, 0);
  for (int it=0; it<NCH; it+=2){
    LOADS(As1, Bs01, Bs11, it+1);
    COMP(As0, Bs00, Bs10);
    if (it+2 < NCH) LOADS(As0, Bs00, Bs10, it+2);
    COMP(As1, Bs01, Bs11);
  }
  #undef LOADS
  #undef COMP

  // ---- fused epilogue ----
  int trow = targets[rowBase + (lane & 31)];   // lane rl holds targets[rowBase+rl]
  int tcol0[2], tcol1[2];
  tcol0[0] = targets[colBase0 + l16];
  tcol0[1] = targets[colBase0 + 16 + l16];
  tcol1[0] = hasT1 ? targets[colBase1 + l16]      : 0;
  tcol1[1] = hasT1 ? targets[colBase1 + 16 + l16] : 0;

  float rowMinReg = 2.f, rowMaxReg = -2.f;     // slot regs (lanes l16<8)
  float posA=0.f, negA=0.f, semiA=0.f, diagA=0.f;
  float posB=0.f, negB=0.f, semiB=0.f, diagB=0.f;

  auto epi = [&](const f32x4 (&Cx)[2][2], const int (&tcolx)[2], int colBasex,
                 bool isD, float& posx, float& negx, float& semix, float& diagx){
    float cmin[2] = {2.f, 2.f}, cmax[2] = {-2.f, -2.f};
    #pragma unroll
    for (int mi=0; mi<2; mi++){
      #pragma unroll
      for (int r=0; r<4; r++){
        int rl = mi*16 + quad*4 + r;
        int row = rowBase + rl;
        int tr = __shfl(trow, rl);
        float vmin = 2.f, vmax = -2.f;
        #pragma unroll
        for (int ni=0; ni<2; ni++){
          int col = colBasex + ni*16 + l16;
          float s = Cx[mi][ni][r];
          if (tr == tcolx[ni]){
            float omv = 1.f - s;
            float q = omv*omv;
            posx += q;
            if (tr == 1) semix += q;
            if (row == col) diagx += q;      // only on the diagonal tile
            else {
              vmin = fminf(vmin, s);
              cmin[ni] = fminf(cmin[ni], s);
            }
          } else {
            float c0 = fmaxf(s - 0.2f, 0.f);
            negx += c0*c0;
            vmax = fmaxf(vmax, s);
            cmax[ni] = fmaxf(cmax[ni], s);
          }
        }
        #pragma unroll
        for (int off=1; off<16; off<<=1){
          vmin = fminf(vmin, __shfl_xor(vmin, off));
          vmax = fmaxf(vmax, __shfl_xor(vmax, off));
        }
        if (l16 == mi*4 + r){                // keep into per-lane row slot
          rowMinReg = fminf(rowMinReg, vmin);
          rowMaxReg = fmaxf(rowMaxReg, vmax);
        }
      }
    }
    if (!isD){                               // col contribution (off-diag only)
      #pragma unroll
      for (int ni=0; ni<2; ni++){
        cmin[ni] = fminf(cmin[ni], __shfl_xor(cmin[ni], 16));
        cmin[ni] = fminf(cmin[ni], __shfl_xor(cmin[ni], 32));
        cmax[ni] = fmaxf(cmax[ni], __shfl_xor(cmax[ni], 16));
        cmax[ni] = fmaxf(cmax[ni], __shfl_xor(cmax[ni], 32));
      }
      if (lane < 32){                        // one instr, 32 lanes: col = base+lane
        float cnv = (lane < 16) ? cmin[0] : cmin[1];
        float cxv = (lane < 16) ? cmax[0] : cmax[1];
        atomicMin(&rowMinU[colBasex + lane], mapf(cnv));
        atomicMax(&rowMaxU[colBasex + lane], mapf(cxv));
      }
    }
  };

  epi(C0, tcol0, colBase0, isDiag0, posA, negA, semiA, diagA);
  if (hasT1) epi(C1, tcol1, colBase1, false, posB, negB, semiB, diagB);

  // one batched row-atomic pair for BOTH tiles (32 active lanes)
  if (l16 < 8){
    int row = rowBase + quad*4 + (l16 & 3) + 16*(l16 >> 2);
    atomicMin(&rowMinU[row], mapf(rowMinReg));
    atomicMax(&rowMaxU[row], mapf(rowMaxReg));
  }

  float fac0 = isDiag0 ? 1.f : 2.f;          // x2 is exact in fp
  float pos  = posA*fac0 + posB*2.f;
  float neg  = negA*fac0 + negB*2.f;
  float semi = semiA*fac0 + semiB*2.f;
  float diag = diagA;

  #pragma unroll
  for (int off=32; off; off>>=1){
    pos  += __shfl_xor(pos, off);
    neg  += __shfl_xor(neg, off);
    semi += __shfl_xor(semi, off);
    diag += __shfl_xor(diag, off);
  }
  if (lane == 0)
    *(float4*)(pairPart + bid*4) = make_float4(pos, neg, semi, diag);
}

// ============ k_final: 1024 threads; histogram + reductions + combine ======
__global__ __launch_bounds__(1024) void k_final(const int* __restrict__ targets,
    const int* __restrict__ epoch_p, int B, int nprep, int nblk,
    const float* __restrict__ pairPart, const float* __restrict__ psum,
    const unsigned* rowMinU, const unsigned* rowMaxU, float* out){
  int tid = threadIdx.x, wave = tid>>6, lane = tid&63;
  __shared__ float redf[16][8];
  __shared__ int   redi[16][4];
  __shared__ float tot6[6];
  __shared__ int   cns[3];
  __shared__ float ptot[4];

  // ---- 1) histogram targets (int4 loads) ----
  {
    int c0=0,c1=0,c2=0;
    for (int i4 = tid; i4 < B/4; i4 += 1024){
      int4 tv = ((const int4*)targets)[i4];
      c0 += (tv.x==0)+(tv.y==0)+(tv.z==0)+(tv.w==0);
      c1 += (tv.x==1)+(tv.y==1)+(tv.z==1)+(tv.w==1);
      c2 += (tv.x==2)+(tv.y==2)+(tv.z==2)+(tv.w==2);
    }
    #pragma unroll
    for (int off=32; off; off>>=1){
      c0+=__shfl_xor(c0,off); c1+=__shfl_xor(c1,off); c2+=__shfl_xor(c2,off);
    }
    if (lane==0){ redi[wave][0]=c0; redi[wave][1]=c1; redi[wave][2]=c2; }
  }
  // ---- 2) per-sample partials ----
  {
    float v0=0,v1=0,v2=0,v3=0,v4=0,v5=0;
    for (int s = tid; s < nprep; s += 1024){
      float4 a = *(const float4*)(psum + s*8);
      float4 b = *(const float4*)(psum + s*8 + 4);
      v0+=a.x; v1+=a.y; v2+=a.z; v3+=a.w; v4+=b.x; v5+=b.y;
    }
    #pragma unroll
    for (int off=32; off; off>>=1){
      v0+=__shfl_xor(v0,off); v1+=__shfl_xor(v1,off); v2+=__shfl_xor(v2,off);
      v3+=__shfl_xor(v3,off); v4+=__shfl_xor(v4,off); v5+=__shfl_xor(v5,off);
    }
    if (lane==0){
      redf[wave][0]=v0; redf[wave][1]=v1; redf[wave][2]=v2;
      redf[wave][3]=v3; redf[wave][4]=v4; redf[wave][5]=v5;
    }
  }
  __syncthreads();
  if (tid == 0){
    int c0=0,c1=0,c2=0;
    float v[6]={0,0,0,0,0,0};
    for (int w2=0; w2<16; w2++){
      c0+=redi[w2][0]; c1+=redi[w2][1]; c2+=redi[w2][2];
      for (int j=0;j<6;j++) v[j]+=redf[w2][j];
    }
    cns[0]=c0; cns[1]=c1; cns[2]=c2;
    for (int j=0;j<6;j++) tot6[j]=v[j];
  }
  __syncthreads();

  // ---- 3) pair partials ----
  {
    float p=0,n=0,s2=0,d=0;
    for (int s = tid; s < nblk; s += 1024){
      float4 a = *(const float4*)(pairPart + s*4);
      p+=a.x; n+=a.y; s2+=a.z; d+=a.w;
    }
    #pragma unroll
    for (int off=32; off; off>>=1){
      p+=__shfl_xor(p,off); n+=__shfl_xor(n,off);
      s2+=__shfl_xor(s2,off); d+=__shfl_xor(d,off);
    }
    if (lane==0){ redf[wave][0]=p; redf[wave][1]=n; redf[wave][2]=s2; redf[wave][3]=d; }
  }
  __syncthreads();
  if (tid == 0){
    float a=0,b=0,c=0,e=0;
    for (int w2=0; w2<16; w2++){ a+=redf[w2][0]; b+=redf[w2][1]; c+=redf[w2][2]; e+=redf[w2][3]; }
    ptot[0]=a; ptot[1]=b; ptot[2]=c; ptot[3]=e;
  }
  __syncthreads();

  int n0=cns[0], n1=cns[1], n2=cns[2];

  // ---- 4) triplet ----
  float tsum = 0.f, tcnt = 0.f;
  for (int i = tid; i < B; i += 1024){
    int t = targets[i];
    int nt = (t==0)?n0:((t==1)?n1:n2);
    if (nt - 1 > 0 && B - nt > 0){
      float mn = unmapf(rowMinU[i]);
      float mx = unmapf(rowMaxU[i]);
      float hp = sqrtf(fmaxf(2.f - 2.f*mn, 0.f));
      float hn = sqrtf(fmaxf(2.f - 2.f*mx, 0.f));
      float margin = 1.5f * ((t==1) ? 2.5f : 1.f);
      float tl = fmaxf(hp - hn + margin, 0.f);
      tsum += tl; tcnt += 1.f;
    }
  }
  #pragma unroll
  for (int off=32; off; off>>=1){ tsum += __shfl_xor(tsum, off); tcnt += __shfl_xor(tcnt, off); }
  if (lane==0){ redf[wave][6]=tsum; redf[wave][7]=tcnt; }
  __syncthreads();

  if (tid==0){
    float ts=0, tn=0;
    for (int w2=0; w2<16; w2++){ ts+=redf[w2][6]; tn+=redf[w2][7]; }
    float triplet = (tn > 0.f) ? ts / fmaxf(tn, 1.f) : 0.f;
    float pos=ptot[0], neg=ptot[1], semi=ptot[2], diag=ptot[3];
    float Bf = (float)B;
    float focal = tot6[0] / Bf;
    float ce = tot6[1] / tot6[2];
    float boundary = tot6[3] / (Bf + 1e-8f);
    float contrastive = (pos + neg + 4.f*semi) / (Bf*Bf + 1e-8f);
    long long npl = ((long long)n0*(n0-1) + (long long)n1*(n1-1) + (long long)n2*(n2-1))/2;
    float qsum = (pos - diag) * 0.5f;
    float q = qsum / (float)(npl > 0 ? npl : 1);
    if (n2 > 0) q *= (1.f + 2.5f * ((float)n2 / Bf));
    float quality = (npl > 0) ? q : 0.f;
    int ep = epoch_p[0];
    float er = (float)ep / 25.f;
    float ann = fminf(1.f, er*er);
    float evidential = tot6[4]/Bf + ann*0.2f*tot6[5]/Bf;
    float total = 0.4f*focal + 0.3f*ce + 0.15f*boundary
                + 0.1f*contrastive + 0.1f*triplet + 0.1f*quality + 0.1f*evidential;
    out[0] = total;
  }
}

extern "C" void kernel_launch(void* const* d_in, const int* in_sizes, int n_in,
                              void* d_out, int out_size, void* d_ws, size_t ws_size,
                              hipStream_t stream){
  const float* logits   = (const float*)d_in[0];
  const int*   targets  = (const int*)d_in[1];
  const float* features = (const float*)d_in[2];
  const float* alpha    = (const float*)d_in[3];
  const int*   epoch    = (const int*)d_in[4];
  const float* fa       = (const float*)d_in[5];
  const float* cw       = (const float*)d_in[6];
  int B = in_sizes[1];
  int D = in_sizes[2] / B;
  int nprep = B/4;                 // k_prep blocks == psum slots
  int NBY = B / 32;                // 32-row groups
  int PMAX = (NBY + 1) / 2;        // max tile-pairs per row group
  int nblk = NBY * PMAX;           // rectangular pair grid (8192 @ B=4096)

  char* ws = (char*)d_ws;
  float*    psum     = (float*)(ws);                          // nprep*8 f32 (32KB)
  float*    pairPart = (float*)(ws + 65536);                  // nblk*4 f32 (128KB)
  unsigned* rowMinU  = (unsigned*)(ws + 65536 + 196608);      // B u32
  unsigned* rowMaxU  = (unsigned*)(ws + 65536 + 196608 + (size_t)B*4);
  __bf16*   fb2      = (__bf16*)(ws + 65536 + 196608 + (size_t)B*8);  // B*D bf16

  k_prep <<<nprep, 256, 0, stream>>>(features, fb2, logits, targets, alpha, fa, cw,
                                     B, D, psum, rowMinU, rowMaxU);
  k_pairs<<<nblk, 64, 0, stream>>>(fb2, targets, B, D, pairPart, rowMinU, rowMaxU);
  k_final<<<1, 1024, 0, stream>>>(targets, epoch, B, nprep, nblk, pairPart, psum,
                                  rowMinU, rowMaxU, (float*)d_out);
}